// Round 5
// baseline (3163.618 us; speedup 1.0000x reference)
//
#include <hip/hip_runtime.h>
#include <math.h>

#define Bz 32
#define Tz 512
#define Ez 256
#define Hz 512
#define FCH 446   // 180 conv + 10 rev + 256 x

__device__ __forceinline__ float sigf(float x){ return 1.0f/(1.0f + __expf(-x)); }
__device__ __forceinline__ float tanhfast(float x){ return 1.0f - 2.0f/(__expf(2.0f*x) + 1.0f); }

// ---------------- WhT transpose: WhT[c*512 + k] = Wh[k*2048 + c] ----------------
__global__ __launch_bounds__(256) void k_transpose_wh(const float* __restrict__ Wh, float* __restrict__ WhT){
  int idx = blockIdx.x*256 + threadIdx.x;      // 512*2048 = 1,048,576
  int k = idx >> 11, c = idx & 2047;
  WhT[c*512 + k] = Wh[idx];
}

// ---------------- conv (3 kernels, SAME pad) + rxw = x_rev @ rev_Wx + x-copy into feat ----
__global__ __launch_bounds__(256) void k_conv(
    const float* __restrict__ x,
    const float* __restrict__ w1, const float* __restrict__ b1,
    const float* __restrict__ w2, const float* __restrict__ b2,
    const float* __restrict__ w3, const float* __restrict__ b3,
    const float* __restrict__ rwx,
    float* __restrict__ feat, float* __restrict__ rxw)
{
  __shared__ __align__(16) float xs[256*40];   // xs[e*40 + i] = x[b][t0-2+i], i in 0..35
  int b  = blockIdx.x >> 4;
  int t0 = (blockIdx.x & 15) * 32;
  int tid = threadIdx.x;
  for (int i = 0; i < 36; ++i){
    int t = t0 - 2 + i;
    xs[tid*40 + i] = (t >= 0 && t < Tz) ? x[(b*Tz + t)*Ez + tid] : 0.0f;
  }
  __syncthreads();
  // x-part of d0 input: feat[t][b][190+e] = x[b][t][e]
  for (int i = 0; i < 32; ++i){
    int t = t0 + i;
    feat[((size_t)t*Bz + b)*FCH + 190 + tid] = xs[tid*40 + i + 2];
  }
  int tq = tid & 7, cs = tid >> 3;             // 8 t-quads x 32 c-slots
  float acc[6][4];
  float racc[2][4];
  #pragma unroll
  for (int ci = 0; ci < 6; ++ci){
    int c = cs + 32*ci;
    float bv = 0.0f;
    if (c < 60) bv = b1[c];
    else if (c < 120) bv = b2[c-60];
    else if (c < 180) bv = b3[c-120];
    acc[ci][0]=acc[ci][1]=acc[ci][2]=acc[ci][3]=bv;
  }
  #pragma unroll
  for (int ji = 0; ji < 2; ++ji){ racc[ji][0]=racc[ji][1]=racc[ji][2]=racc[ji][3]=0.0f; }

  for (int e = 0; e < 256; ++e){
    const float* xr = &xs[e*40 + 4*tq];
    float4 wa = *(const float4*)(xr);
    float4 wb = *(const float4*)(xr + 4);
    float wd[8] = {wa.x, wa.y, wa.z, wa.w, wb.x, wb.y, wb.z, wb.w};
    #pragma unroll
    for (int ci = 0; ci < 6; ++ci){
      int c = cs + 32*ci;
      if (c < 60){
        #pragma unroll
        for (int k = 0; k < 3; ++k){
          float wv = w1[(k*256 + e)*60 + c];
          #pragma unroll
          for (int j = 0; j < 4; ++j) acc[ci][j] = fmaf(wd[1 + j + k], wv, acc[ci][j]);
        }
      } else if (c < 120){
        int cc = c - 60;
        #pragma unroll
        for (int k = 0; k < 4; ++k){
          float wv = w2[(k*256 + e)*60 + cc];
          #pragma unroll
          for (int j = 0; j < 4; ++j) acc[ci][j] = fmaf(wd[1 + j + k], wv, acc[ci][j]);
        }
      } else if (c < 180){
        int cc = c - 120;
        #pragma unroll
        for (int k = 0; k < 5; ++k){
          float wv = w3[(k*256 + e)*60 + cc];
          #pragma unroll
          for (int j = 0; j < 4; ++j) acc[ci][j] = fmaf(wd[j + k], wv, acc[ci][j]);
        }
      }
    }
    #pragma unroll
    for (int ji = 0; ji < 2; ++ji){
      int jc = cs + 32*ji;
      if (jc < 40){
        float wv = rwx[e*40 + jc];
        #pragma unroll
        for (int j = 0; j < 4; ++j) racc[ji][j] = fmaf(wd[2 + j], wv, racc[ji][j]);
      }
    }
  }
  #pragma unroll
  for (int ci = 0; ci < 6; ++ci){
    int c = cs + 32*ci;
    if (c < 180){
      #pragma unroll
      for (int j = 0; j < 4; ++j){
        int t = t0 + 4*tq + j;
        if (t >= 1) feat[((size_t)(t-1)*Bz + b)*FCH + c] = acc[ci][j];
      }
    }
  }
  #pragma unroll
  for (int ji = 0; ji < 2; ++ji){
    int jc = cs + 32*ji;
    if (jc < 40){
      #pragma unroll
      for (int j = 0; j < 4; ++j){
        int t = t0 + 4*tq + j;
        rxw[((size_t)(511 - t)*Bz + b)*40 + jc] = racc[ji][j];
      }
    }
  }
}

// ---------------- reverse LSTM (hidden 10), one wave per batch row ----------------
__global__ __launch_bounds__(64) void k_rev(const float* __restrict__ rxw,
    const float* __restrict__ revWh, const float* __restrict__ revb, float* __restrict__ feat){
  int b = blockIdx.x;
  int j = threadIdx.x;
  float wreg[10];
  float bias = 0.0f;
  #pragma unroll
  for (int k = 0; k < 10; ++k) wreg[k] = 0.0f;
  if (j < 40){
    bias = revb[j];
    #pragma unroll
    for (int k = 0; k < 10; ++k) wreg[k] = revWh[k*40 + j];
  }
  float h[10];
  #pragma unroll
  for (int k = 0; k < 10; ++k) h[k] = 0.0f;
  float c = 0.0f;
  for (int s = 0; s < Tz; ++s){
    float z = bias + ((j < 40) ? rxw[(s*Bz + b)*40 + j] : 0.0f);
    #pragma unroll
    for (int k = 0; k < 10; ++k) z = fmaf(h[k], wreg[k], z);
    float a = (j >= 20 && j < 30) ? tanhfast(z) : sigf(z);
    float af = __shfl(a, j + 10);
    float ag = __shfl(a, j + 20);
    float ao = __shfl(a, j + 30);
    if (j < 10) c = af*c + a*ag;
    float hn = ao * tanhfast(c);
    #pragma unroll
    for (int k = 0; k < 10; ++k) h[k] = __shfl(hn, k);
    if (j < 10 && s >= 1) feat[((size_t)(s-1)*Bz + b)*FCH + 180 + j] = hn;
  }
}

// ---------------- hid = relu(feat @ d0_W + d0_b): 32 rows x 100 cols per block ----------------
__global__ __launch_bounds__(256) void k_hid(const float* __restrict__ feat,
    const float* __restrict__ d0W, const float* __restrict__ d0b, float* __restrict__ hid){
  __shared__ __align__(16) float fT[446*36];   // fT[ch*36 + r]
  int r0 = blockIdx.x * 32;
  int tid = threadIdx.x;
  for (int r = 0; r < 32; ++r){
    fT[tid*36 + r] = feat[(size_t)(r0 + r)*FCH + tid];
    if (tid < 190) fT[(tid + 256)*36 + r] = feat[(size_t)(r0 + r)*FCH + tid + 256];
  }
  __syncthreads();
  int cs = tid & 31, rq = tid >> 5;            // 32 c-slots (4 cols each), 8 row-quads
  if (cs < 25){
    float4 accv[4];
    #pragma unroll
    for (int jc = 0; jc < 4; ++jc) accv[jc] = make_float4(0.f,0.f,0.f,0.f);
    for (int k = 0; k < 446; ++k){
      float4 xv = *(const float4*)&fT[k*36 + 4*rq];
      float4 wv = *(const float4*)&d0W[k*100 + 4*cs];
      accv[0].x = fmaf(xv.x, wv.x, accv[0].x); accv[0].y = fmaf(xv.y, wv.x, accv[0].y);
      accv[0].z = fmaf(xv.z, wv.x, accv[0].z); accv[0].w = fmaf(xv.w, wv.x, accv[0].w);
      accv[1].x = fmaf(xv.x, wv.y, accv[1].x); accv[1].y = fmaf(xv.y, wv.y, accv[1].y);
      accv[1].z = fmaf(xv.z, wv.y, accv[1].z); accv[1].w = fmaf(xv.w, wv.y, accv[1].w);
      accv[2].x = fmaf(xv.x, wv.z, accv[2].x); accv[2].y = fmaf(xv.y, wv.z, accv[2].y);
      accv[2].z = fmaf(xv.z, wv.z, accv[2].z); accv[2].w = fmaf(xv.w, wv.z, accv[2].w);
      accv[3].x = fmaf(xv.x, wv.w, accv[3].x); accv[3].y = fmaf(xv.y, wv.w, accv[3].y);
      accv[3].z = fmaf(xv.z, wv.w, accv[3].z); accv[3].w = fmaf(xv.w, wv.w, accv[3].w);
    }
    #pragma unroll
    for (int i = 0; i < 4; ++i){
      int row = r0 + 4*rq + i;
      float4 o;
      float vi[4] = { i==0?accv[0].x:(i==1?accv[0].y:(i==2?accv[0].z:accv[0].w)),
                      i==0?accv[1].x:(i==1?accv[1].y:(i==2?accv[1].z:accv[1].w)),
                      i==0?accv[2].x:(i==1?accv[2].y:(i==2?accv[2].z:accv[2].w)),
                      i==0?accv[3].x:(i==1?accv[3].y:(i==2?accv[3].z:accv[3].w)) };
      o.x = fmaxf(vi[0] + d0b[4*cs+0], 0.0f);
      o.y = fmaxf(vi[1] + d0b[4*cs+1], 0.0f);
      o.z = fmaxf(vi[2] + d0b[4*cs+2], 0.0f);
      o.w = fmaxf(vi[3] + d0b[4*cs+3], 0.0f);
      *(float4*)&hid[(size_t)row*100 + 4*cs] = o;
    }
  }
}

// ---------------- pi + gumbel softmax -> d0,d1 (64 rows per block) ----------------
__global__ __launch_bounds__(128) void k_pi(const float* __restrict__ hid,
    const float* __restrict__ d1W, const float* __restrict__ d1b,
    const float* __restrict__ gum, float* __restrict__ d0a, float* __restrict__ d1a){
  __shared__ float hidL[64*100];
  int r0 = blockIdx.x * 64;
  int tid = threadIdx.x;
  for (int i = 0; i < 50; ++i) hidL[tid + 128*i] = hid[(size_t)r0*100 + tid + 128*i];
  __syncthreads();
  int r = tid >> 1, pp = tid & 1;
  float s = d1b[pp];
  for (int m = 0; m < 100; ++m) s = fmaf(hidL[r*100 + m], d1W[m*2 + pp], s);
  int row = r0 + r;
  float a = (s + gum[row*2 + pp]) / 1e-5f;
  float other = __shfl_xor(a, 1);
  float mx = fmaxf(a, other);
  float ea = expf(a - mx), eb = expf(other - mx);
  float d = ea / (ea + eb);
  if (pp == 0) d0a[row] = d; else d1a[row] = d;
}

// ---------------- xzG[((g*T + t)*2048 + col)*4 + b'] = x[b][t] @ cell_Wx + cell_b ----------
// Per-group-blocked layout (each 128B line -> one scan block / one XCD). Wx stream is
// register double-buffered to hide L2 latency.
__global__ __launch_bounds__(256) void k_xz(const float* __restrict__ x,
    const float* __restrict__ Wx, const float* __restrict__ cb, float* __restrict__ xzG){
  __shared__ __align__(16) float xT[256*36];   // xT[e*36 + b]
  int t  = blockIdx.x & 511;
  int c0 = (blockIdx.x >> 9) * 128;
  int tid = threadIdx.x;
  for (int b = 0; b < 32; ++b){
    xT[tid*36 + b] = x[(b*Tz + t)*Ez + tid];
  }
  __syncthreads();
  int cs = tid & 31, rq = tid >> 5;            // 32 col-slots (4 cols), 8 batch-quads (=groups)
  float4 accv[4];
  #pragma unroll
  for (int jc = 0; jc < 4; ++jc) accv[jc] = make_float4(0.f,0.f,0.f,0.f);
  float4 wv = *(const float4*)&Wx[c0 + 4*cs];  // e = 0 prefetch
  for (int e = 0; e < 256; ++e){
    float4 wc = wv;
    if (e != 255) wv = *(const float4*)&Wx[(e+1)*2048 + c0 + 4*cs];
    float4 xv = *(const float4*)&xT[e*36 + 4*rq];
    accv[0].x = fmaf(xv.x, wc.x, accv[0].x); accv[0].y = fmaf(xv.y, wc.x, accv[0].y);
    accv[0].z = fmaf(xv.z, wc.x, accv[0].z); accv[0].w = fmaf(xv.w, wc.x, accv[0].w);
    accv[1].x = fmaf(xv.x, wc.y, accv[1].x); accv[1].y = fmaf(xv.y, wc.y, accv[1].y);
    accv[1].z = fmaf(xv.z, wc.y, accv[1].z); accv[1].w = fmaf(xv.w, wc.y, accv[1].w);
    accv[2].x = fmaf(xv.x, wc.z, accv[2].x); accv[2].y = fmaf(xv.y, wc.z, accv[2].y);
    accv[2].z = fmaf(xv.z, wc.z, accv[2].z); accv[2].w = fmaf(xv.w, wc.z, accv[2].w);
    accv[3].x = fmaf(xv.x, wc.w, accv[3].x); accv[3].y = fmaf(xv.y, wc.w, accv[3].y);
    accv[3].z = fmaf(xv.z, wc.w, accv[3].z); accv[3].w = fmaf(xv.w, wc.w, accv[3].w);
  }
  #pragma unroll
  for (int jc = 0; jc < 4; ++jc){
    int col = c0 + 4*cs + jc;
    float bv = cb[col];
    float4 o = accv[jc];
    o.x += bv; o.y += bv; o.z += bv; o.w += bv;
    *(float4*)&xzG[(((size_t)rq*Tz + t)*2048 + col)*4] = o;
  }
}

// ---------------- persistent scan kernel v3 ----------------
// 256 blocks x 512 threads (8 waves). g = blockIdx&7 (XCD under round-robin),
// m = blockIdx>>3. Block: batches 4g..4g+3, hidden units [16m,16m+16) = 64 z-cols.
// Wave w owns cols 8w..8w+7 (wreg 64 VGPR); lane = kseg (8 k each) -> whole K inside
// the wave. 64 partials/z reduced to 8 IN REGISTERS by a 3-round value-splitting
// shfl butterfly, so LDS traffic/step is ~120 instructions (round-4 was ~520 and
// 8-way-conflicted). hL is XOR-swizzled (q^((q>>3)&3)) => stride-8 lane reads are
// 2-way (free). Cross-block h exchange: RELAXED agent-scope atomics only.
__global__ __launch_bounds__(512, 2) void k_scan(
    const float* __restrict__ WhT, const float* __restrict__ xzG,
    const float* __restrict__ d0a, const float* __restrict__ d1a,
    float* __restrict__ hG,              // [8 groups][2 bufs][4*512]
    unsigned int* __restrict__ barc,     // [8] counters, stride 64 uints
    float* __restrict__ out)
{
  __shared__ __align__(16) float hL[4*520];    // swizzled h, row stride 520 (130 quads)
  __shared__ __align__(16) float part[8*260];  // 8 kgroups x 64 cols x 4 b, stride 260
  __shared__ float zL[256];
  __shared__ float hcandL[64];

  int tid = threadIdx.x;
  int g = blockIdx.x & 7;
  int m = blockIdx.x >> 3;
  int w = tid >> 6;                      // wave 0..7
  int lane = tid & 63;                   // = kseg

  // one-time: weights into VGPRs: wreg[ci][j] = Wh^T[col(8w+ci)][lane*8+j]
  float wreg[8][8];
  #pragma unroll
  for (int ci = 0; ci < 8; ++ci){
    int c = 8*w + ci;
    int col = ((c >> 4) << 9) + (m << 4) + (c & 15);
    const float4* wp = (const float4*)(WhT + (size_t)col*512 + lane*8);
    float4 a = wp[0], bq = wp[1];
    wreg[ci][0]=a.x;  wreg[ci][1]=a.y;  wreg[ci][2]=a.z;  wreg[ci][3]=a.w;
    wreg[ci][4]=bq.x; wreg[ci][5]=bq.y; wreg[ci][6]=bq.z; wreg[ci][7]=bq.w;
  }

  // swizzled LDS addresses for this lane's two h quads (k = lane*8 .. +8)
  int q0 = 2*lane;
  int sw = (q0 >> 3) & 3;
  int p0 = ((q0  ) ^ sw) << 2;           // float offset within row
  int p1 = ((q0+1) ^ sw) << 2;

  // staging role: thread stages quad qg = tid (b = tid>>7, q = tid&127)
  int stb = tid >> 7, stq = tid & 127;
  int stp = (stq ^ ((stq >> 3) & 3)) << 2;
  const int hrow = 520;

  // reducer xz address (tid<256): z = (colg = tid>>2, b = tid&3)
  int rcg = tid >> 2, rb = tid & 3;
  int rcol = ((rcg >> 4) << 9) + (m << 4) + (rcg & 15);
  size_t xzbase = ((size_t)g*Tz)*8192 + (size_t)rcol*4 + rb;

  unsigned int* cnt = barc + g*64;
  float* hg0 = hG + (size_t)(g*2 + 0) * (4*512);
  float* hg1 = hG + (size_t)(g*2 + 1) * (4*512);

  float c_reg = 0.0f;                    // cell state (tid<64: bb=tid&3, jl=tid>>2)

  for (int t = 0; t < Tz; ++t){
    const float* hcur = (t & 1) ? hg1 : hg0;
    float*       hnxt = (t & 1) ? hg0 : hg1;

    // ---- stage group h (gen t) into swizzled hL ----
    if (t == 0){
      *(float4*)&hL[stb*hrow + stp] = make_float4(0.f,0.f,0.f,0.f);
    } else {
      const float* src = hcur + stb*512 + stq*4;
      float4 v;
      v.x = __hip_atomic_load(src+0, __ATOMIC_RELAXED, __HIP_MEMORY_SCOPE_AGENT);
      v.y = __hip_atomic_load(src+1, __ATOMIC_RELAXED, __HIP_MEMORY_SCOPE_AGENT);
      v.z = __hip_atomic_load(src+2, __ATOMIC_RELAXED, __HIP_MEMORY_SCOPE_AGENT);
      v.w = __hip_atomic_load(src+3, __ATOMIC_RELAXED, __HIP_MEMORY_SCOPE_AGENT);
      *(float4*)&hL[stb*hrow + stp] = v;
    }
    float xzv = 0.0f;
    if (tid < 256) xzv = xzG[xzbase + (size_t)t*8192];
    float dv0 = 0.0f, dv1 = 0.0f;
    if (tid < 64){
      dv0 = d0a[t*32 + ((g << 2) + (tid & 3))];
      dv1 = d1a[t*32 + ((g << 2) + (tid & 3))];
    }
    __syncthreads();

    // ---- matvec: acc[8 cols][4 b] over k in [lane*8, lane*8+8) ----
    float acc[8][4];
    #pragma unroll
    for (int ci = 0; ci < 8; ++ci)
      #pragma unroll
      for (int b = 0; b < 4; ++b) acc[ci][b] = 0.0f;
    #pragma unroll
    for (int b = 0; b < 4; ++b){
      const float* hr = &hL[b*hrow];
      float4 h0 = *(const float4*)(hr + p0);
      float4 h1 = *(const float4*)(hr + p1);
      float hv[8] = {h0.x,h0.y,h0.z,h0.w,h1.x,h1.y,h1.z,h1.w};
      #pragma unroll
      for (int j = 0; j < 8; ++j){
        #pragma unroll
        for (int ci = 0; ci < 8; ++ci)
          acc[ci][b] = fmaf(wreg[ci][j], hv[j], acc[ci][b]);
      }
    }

    // ---- value-splitting butterfly: 64 partials/z -> 8, in registers ----
    // round 1 (mask 1): keep 4-col half selected by lane&1
    float v16[16];
    {
      bool hi = (lane & 1);
      #pragma unroll
      for (int i = 0; i < 16; ++i){
        int ci = i >> 2, b = i & 3;
        float keep = hi ? acc[4+ci][b] : acc[ci][b];
        float send = hi ? acc[ci][b]   : acc[4+ci][b];
        v16[i] = keep + __shfl_xor(send, 1);
      }
    }
    // round 2 (mask 2)
    float v8[8];
    {
      bool hi = (lane & 2);
      #pragma unroll
      for (int i = 0; i < 8; ++i){
        float keep = hi ? v16[8+i] : v16[i];
        float send = hi ? v16[i]   : v16[8+i];
        v8[i] = keep + __shfl_xor(send, 2);
      }
    }
    // round 3 (mask 4)
    float v4[4];
    {
      bool hi = (lane & 4);
      #pragma unroll
      for (int b = 0; b < 4; ++b){
        float keep = hi ? v8[4+b] : v8[b];
        float send = hi ? v8[b]   : v8[4+b];
        v4[b] = keep + __shfl_xor(send, 4);
      }
    }
    // lane now holds z-partial (col = 8w + e(lane&7), b=0..3) summed over k-block lane>>3
    {
      int e = ((lane & 1) << 2) | (lane & 2) | ((lane >> 2) & 1);
      float* pw = &part[(lane >> 3)*260 + ((8*w + e) << 2)];
      *(float4*)pw = make_float4(v4[0], v4[1], v4[2], v4[3]);
    }
    __syncthreads();

    // ---- final reduce: 8 partials per z ----
    if (tid < 256){
      float s0 = part[0*260 + tid] + part[1*260 + tid];
      float s1 = part[2*260 + tid] + part[3*260 + tid];
      float s2 = part[4*260 + tid] + part[5*260 + tid];
      float s3 = part[6*260 + tid] + part[7*260 + tid];
      zL[tid] = (s0+s1)+(s2+s3) + xzv;
    }
    __syncthreads();

    // ---- gates + publish (wave 0) ----
    if (tid < 64){
      int jl = tid >> 2, bb = tid & 3;
      float zi = zL[      (jl << 2) + bb];
      float zf = zL[ 64 + (jl << 2) + bb];
      float zg = zL[128 + (jl << 2) + bb];
      float zo = zL[192 + (jl << 2) + bb];
      int hk = (m << 4) + jl;
      int hq = hk >> 2;
      int hph = (hq ^ ((hq >> 3) & 3)) << 2;
      float hold = hL[bb*hrow + hph + (hk & 3)];
      float ccand = sigf(zf)*c_reg + sigf(zi)*tanhfast(zg);
      float hcand = sigf(zo)*tanhfast(ccand);
      c_reg = dv0*ccand + dv1*c_reg;
      float hnew = dv0*hcand + dv1*hold;
      hcandL[(bb << 4) + jl] = hcand;
      __hip_atomic_store(hnxt + bb*512 + hk, hnew,
                         __ATOMIC_RELAXED, __HIP_MEMORY_SCOPE_AGENT);
    }
    __syncthreads();                     // drains wave 0's publish (vmcnt) before counter bump

    // out store by wave 1 (overlaps tid0's barrier wait)
    if (tid >= 64 && tid < 80){
      int idx = tid - 64; int bb = idx >> 2, q = idx & 3;
      float4 v = *(const float4*)&hcandL[(bb << 4) + 4*q];
      *(float4*)(out + (size_t)((g << 2) + bb)*(Tz*Hz) + (size_t)t*Hz + (m << 4) + 4*q) = v;
    }
    if (t < Tz-1){
      if (tid == 0){
        __hip_atomic_fetch_add(cnt, 1u, __ATOMIC_RELAXED, __HIP_MEMORY_SCOPE_AGENT);
        unsigned int target = 32u*(unsigned)(t+1);
        while (__hip_atomic_load(cnt, __ATOMIC_RELAXED, __HIP_MEMORY_SCOPE_AGENT) < target)
          __builtin_amdgcn_s_sleep(1);
      }
      __syncthreads();
    }
  }
}

extern "C" void kernel_launch(void* const* d_in, const int* in_sizes, int n_in,
                              void* d_out, int out_size, void* d_ws, size_t ws_size,
                              hipStream_t stream)
{
  const float* x       = (const float*)d_in[0];
  const float* conv1_w = (const float*)d_in[1];
  const float* conv1_b = (const float*)d_in[2];
  const float* conv2_w = (const float*)d_in[3];
  const float* conv2_b = (const float*)d_in[4];
  const float* conv3_w = (const float*)d_in[5];
  const float* conv3_b = (const float*)d_in[6];
  const float* rev_Wx  = (const float*)d_in[7];
  const float* rev_Wh  = (const float*)d_in[8];
  const float* rev_b   = (const float*)d_in[9];
  const float* d0_W    = (const float*)d_in[10];
  const float* d0_b    = (const float*)d_in[11];
  const float* d1_W    = (const float*)d_in[12];
  const float* d1_b    = (const float*)d_in[13];
  const float* cell_Wx = (const float*)d_in[14];
  const float* cell_Wh = (const float*)d_in[15];
  const float* cell_b  = (const float*)d_in[16];
  const float* gumbel  = (const float*)d_in[17];
  float* out = (float*)d_out;

  char* ws = (char*)d_ws;
  size_t off = 0;
  float* xzG  = (float*)(ws + off); off += (size_t)Tz*2048*Bz*4;       // 134 MB
  float* feat = (float*)(ws + off); off += (size_t)Tz*Bz*FCH*4;        // 29 MB
  float* WhT  = (float*)(ws + off); off += (size_t)Hz*2048*4;          // 4 MB
  float* rxw  = (float*)(ws + off); off += (size_t)Tz*Bz*40*4;         // 2.6 MB
  float* hid  = (float*)(ws + off); off += (size_t)Tz*Bz*100*4;        // 6.5 MB
  float* d0a  = (float*)(ws + off); off += (size_t)Tz*Bz*4;
  float* d1a  = (float*)(ws + off); off += (size_t)Tz*Bz*4;
  float* hG   = (float*)(ws + off); off += (size_t)8*2*4*512*4;        // 128 KB
  unsigned int* barc = (unsigned int*)(ws + off); off += 8*64*4;       // 2 KB

  // zero-init: feat row T-1 (ff tail zeros; k_conv writes its x-part), counters
  hipMemsetAsync(feat + (size_t)(Tz-1)*Bz*FCH, 0, Bz*FCH*4, stream);
  hipMemsetAsync(barc, 0, 8*64*4, stream);

  k_transpose_wh<<<4096, 256, 0, stream>>>(cell_Wh, WhT);
  k_conv<<<512, 256, 0, stream>>>(x, conv1_w, conv1_b, conv2_w, conv2_b,
                                  conv3_w, conv3_b, rev_Wx, feat, rxw);
  k_rev<<<32, 64, 0, stream>>>(rxw, rev_Wh, rev_b, feat);
  k_hid<<<512, 256, 0, stream>>>(feat, d0_W, d0_b, hid);
  k_pi<<<256, 128, 0, stream>>>(hid, d1_W, d1_b, gumbel, d0a, d1a);
  k_xz<<<8192, 256, 0, stream>>>(x, cell_Wx, cell_b, xzG);

  k_scan<<<256, 512, 0, stream>>>(WhT, xzG, d0a, d1a, hG, barc, out);
}

// Round 6
// 2935.404 us; speedup vs baseline: 1.0777x; 1.0777x over previous
//
#include <hip/hip_runtime.h>
#include <math.h>

#define Bz 32
#define Tz 512
#define Ez 256
#define Hz 512
#define FCH 446   // 180 conv + 10 rev + 256 x

__device__ __forceinline__ float sigf(float x){ return 1.0f/(1.0f + __expf(-x)); }
__device__ __forceinline__ float tanhfast(float x){ return 1.0f - 2.0f/(__expf(2.0f*x) + 1.0f); }

// ---------------- conv (3 kernels, SAME pad) + rxw = x_rev @ rev_Wx + x-copy into feat ----
__global__ __launch_bounds__(256) void k_conv(
    const float* __restrict__ x,
    const float* __restrict__ w1, const float* __restrict__ b1,
    const float* __restrict__ w2, const float* __restrict__ b2,
    const float* __restrict__ w3, const float* __restrict__ b3,
    const float* __restrict__ rwx,
    float* __restrict__ feat, float* __restrict__ rxw)
{
  __shared__ __align__(16) float xs[256*40];   // xs[e*40 + i] = x[b][t0-2+i], i in 0..35
  int b  = blockIdx.x >> 4;
  int t0 = (blockIdx.x & 15) * 32;
  int tid = threadIdx.x;
  for (int i = 0; i < 36; ++i){
    int t = t0 - 2 + i;
    xs[tid*40 + i] = (t >= 0 && t < Tz) ? x[(b*Tz + t)*Ez + tid] : 0.0f;
  }
  __syncthreads();
  // x-part of d0 input: feat[t][b][190+e] = x[b][t][e]
  for (int i = 0; i < 32; ++i){
    int t = t0 + i;
    feat[((size_t)t*Bz + b)*FCH + 190 + tid] = xs[tid*40 + i + 2];
  }
  int tq = tid & 7, cs = tid >> 3;             // 8 t-quads x 32 c-slots
  float acc[6][4];
  float racc[2][4];
  #pragma unroll
  for (int ci = 0; ci < 6; ++ci){
    int c = cs + 32*ci;
    float bv = 0.0f;
    if (c < 60) bv = b1[c];
    else if (c < 120) bv = b2[c-60];
    else if (c < 180) bv = b3[c-120];
    acc[ci][0]=acc[ci][1]=acc[ci][2]=acc[ci][3]=bv;
  }
  #pragma unroll
  for (int ji = 0; ji < 2; ++ji){ racc[ji][0]=racc[ji][1]=racc[ji][2]=racc[ji][3]=0.0f; }

  for (int e = 0; e < 256; ++e){
    const float* xr = &xs[e*40 + 4*tq];
    float4 wa = *(const float4*)(xr);
    float4 wb = *(const float4*)(xr + 4);
    float wd[8] = {wa.x, wa.y, wa.z, wa.w, wb.x, wb.y, wb.z, wb.w};
    #pragma unroll
    for (int ci = 0; ci < 6; ++ci){
      int c = cs + 32*ci;
      if (c < 60){
        #pragma unroll
        for (int k = 0; k < 3; ++k){
          float wv = w1[(k*256 + e)*60 + c];
          #pragma unroll
          for (int j = 0; j < 4; ++j) acc[ci][j] = fmaf(wd[1 + j + k], wv, acc[ci][j]);
        }
      } else if (c < 120){
        int cc = c - 60;
        #pragma unroll
        for (int k = 0; k < 4; ++k){
          float wv = w2[(k*256 + e)*60 + cc];
          #pragma unroll
          for (int j = 0; j < 4; ++j) acc[ci][j] = fmaf(wd[1 + j + k], wv, acc[ci][j]);
        }
      } else if (c < 180){
        int cc = c - 120;
        #pragma unroll
        for (int k = 0; k < 5; ++k){
          float wv = w3[(k*256 + e)*60 + cc];
          #pragma unroll
          for (int j = 0; j < 4; ++j) acc[ci][j] = fmaf(wd[j + k], wv, acc[ci][j]);
        }
      }
    }
    #pragma unroll
    for (int ji = 0; ji < 2; ++ji){
      int jc = cs + 32*ji;
      if (jc < 40){
        float wv = rwx[e*40 + jc];
        #pragma unroll
        for (int j = 0; j < 4; ++j) racc[ji][j] = fmaf(wd[2 + j], wv, racc[ji][j]);
      }
    }
  }
  #pragma unroll
  for (int ci = 0; ci < 6; ++ci){
    int c = cs + 32*ci;
    if (c < 180){
      #pragma unroll
      for (int j = 0; j < 4; ++j){
        int t = t0 + 4*tq + j;
        if (t >= 1) feat[((size_t)(t-1)*Bz + b)*FCH + c] = acc[ci][j];
      }
    }
  }
  #pragma unroll
  for (int ji = 0; ji < 2; ++ji){
    int jc = cs + 32*ji;
    if (jc < 40){
      #pragma unroll
      for (int j = 0; j < 4; ++j){
        int t = t0 + 4*tq + j;
        rxw[((size_t)(511 - t)*Bz + b)*40 + jc] = racc[ji][j];
      }
    }
  }
}

// ---------------- reverse LSTM (hidden 10), one wave per batch row ----------------
__global__ __launch_bounds__(64) void k_rev(const float* __restrict__ rxw,
    const float* __restrict__ revWh, const float* __restrict__ revb, float* __restrict__ feat){
  int b = blockIdx.x;
  int j = threadIdx.x;
  float wreg[10];
  float bias = 0.0f;
  #pragma unroll
  for (int k = 0; k < 10; ++k) wreg[k] = 0.0f;
  if (j < 40){
    bias = revb[j];
    #pragma unroll
    for (int k = 0; k < 10; ++k) wreg[k] = revWh[k*40 + j];
  }
  float h[10];
  #pragma unroll
  for (int k = 0; k < 10; ++k) h[k] = 0.0f;
  float c = 0.0f;
  for (int s = 0; s < Tz; ++s){
    float z = bias + ((j < 40) ? rxw[(s*Bz + b)*40 + j] : 0.0f);
    #pragma unroll
    for (int k = 0; k < 10; ++k) z = fmaf(h[k], wreg[k], z);
    float a = (j >= 20 && j < 30) ? tanhfast(z) : sigf(z);
    float af = __shfl(a, j + 10);
    float ag = __shfl(a, j + 20);
    float ao = __shfl(a, j + 30);
    if (j < 10) c = af*c + a*ag;
    float hn = ao * tanhfast(c);
    #pragma unroll
    for (int k = 0; k < 10; ++k) h[k] = __shfl(hn, k);
    if (j < 10 && s >= 1) feat[((size_t)(s-1)*Bz + b)*FCH + 180 + j] = hn;
  }
}

// ---------------- hid = relu(feat @ d0_W + d0_b): 32 rows x 100 cols per block ----------------
__global__ __launch_bounds__(256) void k_hid(const float* __restrict__ feat,
    const float* __restrict__ d0W, const float* __restrict__ d0b, float* __restrict__ hid){
  __shared__ __align__(16) float fT[446*36];   // fT[ch*36 + r]
  int r0 = blockIdx.x * 32;
  int tid = threadIdx.x;
  for (int r = 0; r < 32; ++r){
    fT[tid*36 + r] = feat[(size_t)(r0 + r)*FCH + tid];
    if (tid < 190) fT[(tid + 256)*36 + r] = feat[(size_t)(r0 + r)*FCH + tid + 256];
  }
  __syncthreads();
  int cs = tid & 31, rq = tid >> 5;            // 32 c-slots (4 cols each), 8 row-quads
  if (cs < 25){
    float4 accv[4];
    #pragma unroll
    for (int jc = 0; jc < 4; ++jc) accv[jc] = make_float4(0.f,0.f,0.f,0.f);
    for (int k = 0; k < 446; ++k){
      float4 xv = *(const float4*)&fT[k*36 + 4*rq];
      float4 wv = *(const float4*)&d0W[k*100 + 4*cs];
      accv[0].x = fmaf(xv.x, wv.x, accv[0].x); accv[0].y = fmaf(xv.y, wv.x, accv[0].y);
      accv[0].z = fmaf(xv.z, wv.x, accv[0].z); accv[0].w = fmaf(xv.w, wv.x, accv[0].w);
      accv[1].x = fmaf(xv.x, wv.y, accv[1].x); accv[1].y = fmaf(xv.y, wv.y, accv[1].y);
      accv[1].z = fmaf(xv.z, wv.y, accv[1].z); accv[1].w = fmaf(xv.w, wv.y, accv[1].w);
      accv[2].x = fmaf(xv.x, wv.z, accv[2].x); accv[2].y = fmaf(xv.y, wv.z, accv[2].y);
      accv[2].z = fmaf(xv.z, wv.z, accv[2].z); accv[2].w = fmaf(xv.w, wv.z, accv[2].w);
      accv[3].x = fmaf(xv.x, wv.w, accv[3].x); accv[3].y = fmaf(xv.y, wv.w, accv[3].y);
      accv[3].z = fmaf(xv.z, wv.w, accv[3].z); accv[3].w = fmaf(xv.w, wv.w, accv[3].w);
    }
    #pragma unroll
    for (int i = 0; i < 4; ++i){
      int row = r0 + 4*rq + i;
      float4 o;
      float vi[4] = { i==0?accv[0].x:(i==1?accv[0].y:(i==2?accv[0].z:accv[0].w)),
                      i==0?accv[1].x:(i==1?accv[1].y:(i==2?accv[1].z:accv[1].w)),
                      i==0?accv[2].x:(i==1?accv[2].y:(i==2?accv[2].z:accv[2].w)),
                      i==0?accv[3].x:(i==1?accv[3].y:(i==2?accv[3].z:accv[3].w)) };
      o.x = fmaxf(vi[0] + d0b[4*cs+0], 0.0f);
      o.y = fmaxf(vi[1] + d0b[4*cs+1], 0.0f);
      o.z = fmaxf(vi[2] + d0b[4*cs+2], 0.0f);
      o.w = fmaxf(vi[3] + d0b[4*cs+3], 0.0f);
      *(float4*)&hid[(size_t)row*100 + 4*cs] = o;
    }
  }
}

// ---------------- pi + gumbel softmax -> d0,d1 (64 rows per block) ----------------
__global__ __launch_bounds__(128) void k_pi(const float* __restrict__ hid,
    const float* __restrict__ d1W, const float* __restrict__ d1b,
    const float* __restrict__ gum, float* __restrict__ d0a, float* __restrict__ d1a){
  __shared__ float hidL[64*100];
  int r0 = blockIdx.x * 64;
  int tid = threadIdx.x;
  for (int i = 0; i < 50; ++i) hidL[tid + 128*i] = hid[(size_t)r0*100 + tid + 128*i];
  __syncthreads();
  int r = tid >> 1, pp = tid & 1;
  float s = d1b[pp];
  for (int m = 0; m < 100; ++m) s = fmaf(hidL[r*100 + m], d1W[m*2 + pp], s);
  int row = r0 + r;
  float a = (s + gum[row*2 + pp]) / 1e-5f;
  float other = __shfl_xor(a, 1);
  float mx = fmaxf(a, other);
  float ea = expf(a - mx), eb = expf(other - mx);
  float d = ea / (ea + eb);
  if (pp == 0) d0a[row] = d; else d1a[row] = d;
}

// ---------------- xzG[((g*T + t)*2048 + col)*4 + b'] = x[b][t] @ cell_Wx + cell_b ----------
__global__ __launch_bounds__(256) void k_xz(const float* __restrict__ x,
    const float* __restrict__ Wx, const float* __restrict__ cb, float* __restrict__ xzG){
  __shared__ __align__(16) float xT[256*36];   // xT[e*36 + b]
  int t  = blockIdx.x & 511;
  int c0 = (blockIdx.x >> 9) * 128;
  int tid = threadIdx.x;
  for (int b = 0; b < 32; ++b){
    xT[tid*36 + b] = x[(b*Tz + t)*Ez + tid];
  }
  __syncthreads();
  int cs = tid & 31, rq = tid >> 5;            // 32 col-slots (4 cols), 8 batch-quads (=groups)
  float4 accv[4];
  #pragma unroll
  for (int jc = 0; jc < 4; ++jc) accv[jc] = make_float4(0.f,0.f,0.f,0.f);
  float4 wv = *(const float4*)&Wx[c0 + 4*cs];  // e = 0 prefetch
  for (int e = 0; e < 256; ++e){
    float4 wc = wv;
    if (e != 255) wv = *(const float4*)&Wx[(e+1)*2048 + c0 + 4*cs];
    float4 xv = *(const float4*)&xT[e*36 + 4*rq];
    accv[0].x = fmaf(xv.x, wc.x, accv[0].x); accv[0].y = fmaf(xv.y, wc.x, accv[0].y);
    accv[0].z = fmaf(xv.z, wc.x, accv[0].z); accv[0].w = fmaf(xv.w, wc.x, accv[0].w);
    accv[1].x = fmaf(xv.x, wc.y, accv[1].x); accv[1].y = fmaf(xv.y, wc.y, accv[1].y);
    accv[1].z = fmaf(xv.z, wc.y, accv[1].z); accv[1].w = fmaf(xv.w, wc.y, accv[1].w);
    accv[2].x = fmaf(xv.x, wc.z, accv[2].x); accv[2].y = fmaf(xv.y, wc.z, accv[2].y);
    accv[2].z = fmaf(xv.z, wc.z, accv[2].z); accv[2].w = fmaf(xv.w, wc.z, accv[2].w);
    accv[3].x = fmaf(xv.x, wc.w, accv[3].x); accv[3].y = fmaf(xv.y, wc.w, accv[3].y);
    accv[3].z = fmaf(xv.z, wc.w, accv[3].z); accv[3].w = fmaf(xv.w, wc.w, accv[3].w);
  }
  #pragma unroll
  for (int jc = 0; jc < 4; ++jc){
    int col = c0 + 4*cs + jc;
    float bv = cb[col];
    float4 o = accv[jc];
    o.x += bv; o.y += bv; o.z += bv; o.w += bv;
    *(float4*)&xzG[(((size_t)rq*Tz + t)*2048 + col)*4] = o;
  }
}

// ---------------- persistent scan kernel v4: per-producer tag handshake ----------------
// 256 blocks x 512 threads. g = blockIdx&7 (XCD under round-robin), m = blockIdx>>3.
// Block: batches 4g..4g+3, hidden units [16m,16m+16) = 64 z-cols; Wh slice in VGPRs
// (gathered directly from Wh — no transpose kernel). Cross-block exchange: producer
// stores h slice (relaxed agent), __syncthreads drains vmcnt, then tid0 stores
// tags[g][m]=t+1 (relaxed agent). Consumers: each staging thread busy-polls ITS
// producer's tag then loads that producer's quad — no global counter round trip,
// straggler wait overlaps with data loads from already-done producers.
// Monotonic tags + double-buffered hG: no resets, no fences, no buffer_inv anywhere.
__global__ __launch_bounds__(512, 2) void k_scan(
    const float* __restrict__ Wh, const float* __restrict__ xzG,
    const float* __restrict__ d0a, const float* __restrict__ d1a,
    float* __restrict__ hG,              // [8 groups][2 bufs][4*512]
    unsigned int* __restrict__ tags,     // [8][32]
    float* __restrict__ out)
{
  __shared__ __align__(16) float hL[4*520];    // swizzled h, row stride 520
  __shared__ __align__(16) float part[8*260];  // 8 kgroups x 64 cols x 4 b, stride 260
  __shared__ float zL[256];
  __shared__ float hcandL[64];
  __shared__ float dv0L[2048];                 // [t*4 + bb], staged once
  __shared__ float dv1L[2048];

  int tid = threadIdx.x;
  int g = blockIdx.x & 7;
  int m = blockIdx.x >> 3;
  int w = tid >> 6;                      // wave 0..7
  int lane = tid & 63;                   // = kseg

  // one-time: weights into VGPRs straight from Wh[k][col]:
  // wreg[ci][j] = Wh[(lane*8+j)*2048 + colbase + ci], cols contiguous per wave.
  float wreg[8][8];
  {
    int colbase = ((w >> 1) << 9) + (m << 4) + ((w & 1) << 3);
    #pragma unroll
    for (int j = 0; j < 8; ++j){
      const float4* wp = (const float4*)(Wh + (size_t)(lane*8 + j)*2048 + colbase);
      float4 a = wp[0], bq = wp[1];
      wreg[0][j]=a.x;  wreg[1][j]=a.y;  wreg[2][j]=a.z;  wreg[3][j]=a.w;
      wreg[4][j]=bq.x; wreg[5][j]=bq.y; wreg[6][j]=bq.z; wreg[7][j]=bq.w;
    }
  }
  // one-time: gate coefficients to LDS
  for (int i = tid; i < 2048; i += 512){
    int tt = i >> 2, bb = i & 3;
    dv0L[i] = d0a[tt*32 + (g << 2) + bb];
    dv1L[i] = d1a[tt*32 + (g << 2) + bb];
  }

  // swizzled LDS addresses for this lane's two h quads (k = lane*8 .. +8)
  int q0 = 2*lane;
  int sw = (q0 >> 3) & 3;
  int p0 = ((q0  ) ^ sw) << 2;
  int p1 = ((q0+1) ^ sw) << 2;

  // staging role: thread stages quad (b = tid>>7, q = tid&127); producer = q>>2
  int stb = tid >> 7, stq = tid & 127;
  int stp = (stq ^ ((stq >> 3) & 3)) << 2;
  const int hrow = 520;
  const unsigned int* mytag = tags + (g << 5) + (stq >> 2);

  // reducer xz address (tid<256)
  int rcg = tid >> 2, rb = tid & 3;
  int rcol = ((rcg >> 4) << 9) + (m << 4) + (rcg & 15);
  size_t xzbase = ((size_t)g*Tz)*8192 + (size_t)rcol*4 + rb;

  float* hg0 = hG + (size_t)(g*2 + 0) * (4*512);
  float* hg1 = hG + (size_t)(g*2 + 1) * (4*512);

  float c_reg = 0.0f;                    // cell state (tid<64: bb=tid&3, jl=tid>>2)

  for (int t = 0; t < Tz; ++t){
    const float* hcur = (t & 1) ? hg1 : hg0;
    float*       hnxt = (t & 1) ? hg0 : hg1;

    // ---- stage group h (gen t): poll own producer's tag, then load its quad ----
    if (t == 0){
      *(float4*)&hL[stb*hrow + stp] = make_float4(0.f,0.f,0.f,0.f);
    } else {
      while (__hip_atomic_load(mytag, __ATOMIC_RELAXED, __HIP_MEMORY_SCOPE_AGENT)
             < (unsigned)t) { }
      const float* src = hcur + stb*512 + stq*4;
      float4 v;
      v.x = __hip_atomic_load(src+0, __ATOMIC_RELAXED, __HIP_MEMORY_SCOPE_AGENT);
      v.y = __hip_atomic_load(src+1, __ATOMIC_RELAXED, __HIP_MEMORY_SCOPE_AGENT);
      v.z = __hip_atomic_load(src+2, __ATOMIC_RELAXED, __HIP_MEMORY_SCOPE_AGENT);
      v.w = __hip_atomic_load(src+3, __ATOMIC_RELAXED, __HIP_MEMORY_SCOPE_AGENT);
      *(float4*)&hL[stb*hrow + stp] = v;
    }
    float xzv = 0.0f;
    if (tid < 256) xzv = xzG[xzbase + (size_t)t*8192];
    __syncthreads();

    // ---- matvec: acc[8 cols][4 b] over k in [lane*8, lane*8+8) ----
    float acc[8][4];
    #pragma unroll
    for (int ci = 0; ci < 8; ++ci)
      #pragma unroll
      for (int b = 0; b < 4; ++b) acc[ci][b] = 0.0f;
    #pragma unroll
    for (int b = 0; b < 4; ++b){
      const float* hr = &hL[b*hrow];
      float4 h0 = *(const float4*)(hr + p0);
      float4 h1 = *(const float4*)(hr + p1);
      float hv[8] = {h0.x,h0.y,h0.z,h0.w,h1.x,h1.y,h1.z,h1.w};
      #pragma unroll
      for (int j = 0; j < 8; ++j){
        #pragma unroll
        for (int ci = 0; ci < 8; ++ci)
          acc[ci][b] = fmaf(wreg[ci][j], hv[j], acc[ci][b]);
      }
    }

    // ---- value-splitting butterfly: 64 partials/z -> 8, in registers ----
    float v16[16];
    {
      bool hi = (lane & 1);
      #pragma unroll
      for (int i = 0; i < 16; ++i){
        int ci = i >> 2, b = i & 3;
        float keep = hi ? acc[4+ci][b] : acc[ci][b];
        float send = hi ? acc[ci][b]   : acc[4+ci][b];
        v16[i] = keep + __shfl_xor(send, 1);
      }
    }
    float v8[8];
    {
      bool hi = (lane & 2);
      #pragma unroll
      for (int i = 0; i < 8; ++i){
        float keep = hi ? v16[8+i] : v16[i];
        float send = hi ? v16[i]   : v16[8+i];
        v8[i] = keep + __shfl_xor(send, 2);
      }
    }
    float v4[4];
    {
      bool hi = (lane & 4);
      #pragma unroll
      for (int b = 0; b < 4; ++b){
        float keep = hi ? v8[4+b] : v8[b];
        float send = hi ? v8[b]   : v8[4+b];
        v4[b] = keep + __shfl_xor(send, 4);
      }
    }
    {
      int e = ((lane & 1) << 2) | (lane & 2) | ((lane >> 2) & 1);
      float* pw = &part[(lane >> 3)*260 + ((8*w + e) << 2)];
      *(float4*)pw = make_float4(v4[0], v4[1], v4[2], v4[3]);
    }
    __syncthreads();

    // ---- final reduce: 8 partials per z ----
    if (tid < 256){
      float s0 = part[0*260 + tid] + part[1*260 + tid];
      float s1 = part[2*260 + tid] + part[3*260 + tid];
      float s2 = part[4*260 + tid] + part[5*260 + tid];
      float s3 = part[6*260 + tid] + part[7*260 + tid];
      zL[tid] = (s0+s1)+(s2+s3) + xzv;
    }
    __syncthreads();

    // ---- gates + publish (wave 0) ----
    if (tid < 64){
      int jl = tid >> 2, bb = tid & 3;
      float zi = zL[      (jl << 2) + bb];
      float zf = zL[ 64 + (jl << 2) + bb];
      float zg = zL[128 + (jl << 2) + bb];
      float zo = zL[192 + (jl << 2) + bb];
      float dv0 = dv0L[(t << 2) + bb];
      float dv1 = dv1L[(t << 2) + bb];
      int hk = (m << 4) + jl;
      int hq = hk >> 2;
      int hph = (hq ^ ((hq >> 3) & 3)) << 2;
      float hold = hL[bb*hrow + hph + (hk & 3)];
      float ccand = sigf(zf)*c_reg + sigf(zi)*tanhfast(zg);
      float hcand = sigf(zo)*tanhfast(ccand);
      c_reg = dv0*ccand + dv1*c_reg;
      float hnew = dv0*hcand + dv1*hold;
      hcandL[(bb << 4) + jl] = hcand;
      __hip_atomic_store(hnxt + bb*512 + hk, hnew,
                         __ATOMIC_RELAXED, __HIP_MEMORY_SCOPE_AGENT);
    }
    __syncthreads();                     // drains wave 0's publish (vmcnt) in all waves

    // tag publish (tid0) + out store (wave 1) — both off the next-staging path
    if (tid == 0){
      __hip_atomic_store(tags + (g << 5) + m, (unsigned)(t+1),
                         __ATOMIC_RELAXED, __HIP_MEMORY_SCOPE_AGENT);
    }
    if (tid >= 64 && tid < 80){
      int idx = tid - 64; int bb = idx >> 2, q = idx & 3;
      float4 v = *(const float4*)&hcandL[(bb << 4) + 4*q];
      *(float4*)(out + (size_t)((g << 2) + bb)*(Tz*Hz) + (size_t)t*Hz + (m << 4) + 4*q) = v;
    }
  }
}

extern "C" void kernel_launch(void* const* d_in, const int* in_sizes, int n_in,
                              void* d_out, int out_size, void* d_ws, size_t ws_size,
                              hipStream_t stream)
{
  const float* x       = (const float*)d_in[0];
  const float* conv1_w = (const float*)d_in[1];
  const float* conv1_b = (const float*)d_in[2];
  const float* conv2_w = (const float*)d_in[3];
  const float* conv2_b = (const float*)d_in[4];
  const float* conv3_w = (const float*)d_in[5];
  const float* conv3_b = (const float*)d_in[6];
  const float* rev_Wx  = (const float*)d_in[7];
  const float* rev_Wh  = (const float*)d_in[8];
  const float* rev_b   = (const float*)d_in[9];
  const float* d0_W    = (const float*)d_in[10];
  const float* d0_b    = (const float*)d_in[11];
  const float* d1_W    = (const float*)d_in[12];
  const float* d1_b    = (const float*)d_in[13];
  const float* cell_Wx = (const float*)d_in[14];
  const float* cell_Wh = (const float*)d_in[15];
  const float* cell_b  = (const float*)d_in[16];
  const float* gumbel  = (const float*)d_in[17];
  float* out = (float*)d_out;

  char* ws = (char*)d_ws;
  size_t off = 0;
  float* xzG  = (float*)(ws + off); off += (size_t)Tz*2048*Bz*4;       // 134 MB
  float* feat = (float*)(ws + off); off += (size_t)Tz*Bz*FCH*4;        // 29 MB
  float* rxw  = (float*)(ws + off); off += (size_t)Tz*Bz*40*4;         // 2.6 MB
  float* hid  = (float*)(ws + off); off += (size_t)Tz*Bz*100*4;        // 6.5 MB
  float* d0a  = (float*)(ws + off); off += (size_t)Tz*Bz*4;
  float* d1a  = (float*)(ws + off); off += (size_t)Tz*Bz*4;
  float* hG   = (float*)(ws + off); off += (size_t)8*2*4*512*4;        // 128 KB
  unsigned int* tags = (unsigned int*)(ws + off); off += 8*32*4;       // 1 KB

  // zero-init: feat row T-1 (ff tail zeros; k_conv writes its x-part), tags
  hipMemsetAsync(feat + (size_t)(Tz-1)*Bz*FCH, 0, Bz*FCH*4, stream);
  hipMemsetAsync(tags, 0, 8*32*4, stream);

  k_conv<<<512, 256, 0, stream>>>(x, conv1_w, conv1_b, conv2_w, conv2_b,
                                  conv3_w, conv3_b, rev_Wx, feat, rxw);
  k_rev<<<32, 64, 0, stream>>>(rxw, rev_Wh, rev_b, feat);
  k_hid<<<512, 256, 0, stream>>>(feat, d0_W, d0_b, hid);
  k_pi<<<256, 128, 0, stream>>>(hid, d1_W, d1_b, gumbel, d0a, d1a);
  k_xz<<<8192, 256, 0, stream>>>(x, cell_Wx, cell_b, xzG);

  k_scan<<<256, 512, 0, stream>>>(cell_Wh, xzG, d0a, d1a, hG, tags, out);
}